// Round 8
// baseline (195.371 us; speedup 1.0000x reference)
//
#include <hip/hip_runtime.h>
#include <hip/hip_bf16.h>

typedef _Float16 half8 __attribute__((ext_vector_type(8)));
typedef float f32x4 __attribute__((ext_vector_type(4)));
typedef unsigned uint4e __attribute__((ext_vector_type(4)));
typedef unsigned uint2e __attribute__((ext_vector_type(2)));

#define B_ 16
#define C_ 256
#define D_ 128
#define H_ 64
#define W_ 64
#define N_ 4096   // H*W
#define M_ 1024   // (H/2)*(W/2)
#define NCH 32    // M/32 key chunks

// workspace layout (bytes)
static constexpr size_t WS_PHI   = 0;                                  // fp16 [B][M][C]   8 MB
static constexpr size_t WS_GPOOL = WS_PHI   + (size_t)B_*M_*C_*2;      // fp16 [B][D][M]   4 MB
static constexpr size_t WS_Y     = WS_GPOOL + (size_t)B_*D_*M_*2;      // fp16 [B][N][D]  16 MB
static constexpr size_t WS_BNSUM = WS_Y     + (size_t)B_*N_*D_*2;      // f32  [C]
static constexpr size_t WS_BNSSQ = WS_BNSUM + (size_t)C_*4;            // f32  [C]
static constexpr size_t WS_PSUM  = WS_BNSSQ + (size_t)C_*4;            // f32  [1024][256] 1MB
static constexpr size_t WS_PSSQ  = WS_PSUM  + (size_t)1024*256*4;      // f32  [1024][256] 1MB
static constexpr size_t WS_GW16  = WS_PSSQ  + (size_t)1024*256*4;      // fp16 [D][C] 64KB
static constexpr size_t WS_WW16  = WS_GW16  + (size_t)D_*C_*2;         // fp16 [C][D] 64KB

typedef __attribute__((address_space(3))) void lds_vt;
typedef const __attribute__((address_space(1))) void gbl_vt;

__device__ __forceinline__ void gl2lds16(const void* g, void* s) {
  __builtin_amdgcn_global_load_lds((gbl_vt*)g, (lds_vt*)s, 16, 0, 0);
}

__device__ __forceinline__ unsigned pkrtz(float a, float b) {
  auto v = __builtin_amdgcn_cvt_pkrtz(a, b);   // __fp16 ext_vector(2)
  return __builtin_bit_cast(unsigned, v);
}

// xor-32 lane exchange on the VALU pipe (permlane32_swap) instead of LDS
// (ds_swizzle). Falls back to __shfl_xor if the builtin is unavailable.
__device__ __forceinline__ unsigned xor32_swap(unsigned v) {
#if __has_builtin(__builtin_amdgcn_permlane32_swap)
  auto pr = __builtin_amdgcn_permlane32_swap(v, v, false, false);
  uint2e p = __builtin_bit_cast(uint2e, pr);
  // result: lanes 0..31 need v from hi half (p[1]); lanes 32..63 need lo (p[0])
  return (threadIdx.x & 32) ? p[0] : p[1];
#else
  return __shfl_xor(v, 32, 64);
#endif
}
__device__ __forceinline__ float xor32f(float v) {
  return __builtin_bit_cast(float, xor32_swap(__builtin_bit_cast(unsigned, v)));
}

// ---------------------------------------------------------------------------
// P0: convert weights to fp16 once. gw16[d][c], ww16[c][d].
// ---------------------------------------------------------------------------
__global__ __launch_bounds__(256) void conv16_kernel(
    const float* __restrict__ gw, const float* __restrict__ ww,
    _Float16* __restrict__ gw16, _Float16* __restrict__ ww16) {
  const int i = blockIdx.x*256 + threadIdx.x;   // 0..32767
  gw16[i] = (_Float16)gw[i];
  ww16[i] = (_Float16)ww[i];
}

// ---------------------------------------------------------------------------
// P1+P2 fused v3: LDS-staged x slab (fp16 [256c][130n] padded; all-bank reads),
// coalesced float4 staging (16 VMEM/thread vs 128 scalar). One x pass.
//   phi[b][m][c]   = fp16(maxpool2x2(x))
//   gpool[b][d][m] = fp16(maxpool2x2(g_w *. x) + g_b)
// 512 threads: wn = w&3 n-group, wd = w>>2 d-half. grid (32 row-pairs, 16 b).
// ---------------------------------------------------------------------------
__global__ __launch_bounds__(512, 4) void fused_pre_kernel(
    const float* __restrict__ x, const _Float16* __restrict__ gw16,
    const float* __restrict__ g_b, _Float16* __restrict__ phi,
    _Float16* __restrict__ gpool) {
  const int i = blockIdx.x;            // image row-pair (rows 2i, 2i+1)
  const int b = blockIdx.y;
  const int t = threadIdx.x;
  const int w = t >> 6, l = t & 63, gq = (l >> 4) & 3, c16 = l & 15;
  const int wn = w & 3, wd = w >> 2;

  __shared__ _Float16 x_s[256][130];   // 65 KB; pitch 65 dwords (odd -> all banks)

  // stage: x slab [256 c][128 n] -> fp16 LDS, coalesced float4 loads
  {
    const float* xb = x + (size_t)b*C_*N_ + (size_t)i*128;
#pragma unroll
    for (int it = 0; it < 16; ++it) {
      const int id = it*512 + t;
      const int c = id >> 5, nq = id & 31;
      float4 u = *(const float4*)(xb + (size_t)c*N_ + nq*4);
      unsigned* dst = (unsigned*)&x_s[c][nq*4];
      dst[0] = pkrtz(u.x, u.y);
      dst[1] = pkrtz(u.z, u.w);
    }
  }
  __syncthreads();

  f32x4 acc[4][2];
#pragma unroll
  for (int ds = 0; ds < 4; ++ds) {
    acc[ds][0] = (f32x4){0.f,0.f,0.f,0.f};
    acc[ds][1] = (f32x4){0.f,0.f,0.f,0.f};
  }

  const int nn0 = wn*16 + c16;                 // local n (row 2i); +64 = row 2i+1
  const int mrow = i*32 + wn*8 + (c16 >> 1);

  for (int kk = 0; kk < 8; ++kk) {
    const int c0 = kk*32 + gq*8;
    half8 bf0, bf1;
#pragma unroll
    for (int j = 0; j < 8; ++j) {
      bf0[j] = x_s[c0 + j][nn0];
      bf1[j] = x_s[c0 + j][nn0 + 64];
    }
    if (wd == 0) {
      // phi: vertical pool (bf0 vs bf1) + horizontal lane-pair pool
      half8 pk_;
#pragma unroll
      for (int j = 0; j < 8; ++j) {
        float v = fmaxf((float)bf0[j], (float)bf1[j]);
        v = fmaxf(v, __shfl_xor(v, 1, 64));
        pk_[j] = (_Float16)v;
      }
      if (!(l & 1))
        *(half8*)(phi + ((size_t)b*M_ + mrow)*C_ + c0) = pk_;
    }
#pragma unroll
    for (int ds = 0; ds < 4; ++ds) {
      half8 af = *(const half8*)(gw16 + (size_t)((wd*4 + ds)*16 + c16)*C_ + c0);
      acc[ds][0] = __builtin_amdgcn_mfma_f32_16x16x32_f16(af, bf0, acc[ds][0], 0, 0, 0);
      acc[ds][1] = __builtin_amdgcn_mfma_f32_16x16x32_f16(af, bf1, acc[ds][1], 0, 0, 0);
    }
  }

#pragma unroll
  for (int ds = 0; ds < 4; ++ds) {
#pragma unroll
    for (int r = 0; r < 4; ++r) {
      const int d = (wd*4 + ds)*16 + gq*4 + r;
      float v = fmaxf(acc[ds][0][r], acc[ds][1][r]);
      v = fmaxf(v, __shfl_xor(v, 1, 64));
      if (!(l & 1))
        gpool[((size_t)b*D_ + d)*M_ + mrow] = (_Float16)(v + g_b[d]);
    }
  }
}

// ---------------------------------------------------------------------------
// in-register P -> PV A-fragment build (xor16 via ds_swizzle, xor32 via VALU)
// ---------------------------------------------------------------------------
__device__ __forceinline__ half8 build_pa(const float p0[4], const float p1[4], int gq) {
  unsigned d0 = pkrtz(p0[0], p0[1]);
  unsigned d1 = pkrtz(p0[2], p0[3]);
  unsigned e0 = pkrtz(p1[0], p1[1]);
  unsigned e1 = pkrtz(p1[2], p1[3]);
  unsigned D0 = __shfl_xor(d0, 16, 64), D1 = __shfl_xor(d1, 16, 64);
  unsigned E0 = __shfl_xor(e0, 16, 64), E1 = __shfl_xor(e1, 16, 64);
  const bool lo = gq < 2;
  unsigned s0 = lo ? e0 : d0, s1 = lo ? e1 : d1;
  unsigned s2 = lo ? E0 : D0, s3 = lo ? E1 : D1;
  unsigned R0 = xor32_swap(s0), R1 = xor32_swap(s1);
  unsigned R2 = xor32_swap(s2), R3 = xor32_swap(s3);
  uint4e u;
  u[0] = gq==0 ? d0 : gq==1 ? R2 : gq==2 ? R0 : E0;
  u[1] = gq==0 ? d1 : gq==1 ? R3 : gq==2 ? R1 : E1;
  u[2] = gq==0 ? D0 : gq==1 ? R0 : gq==2 ? R2 : e0;
  u[3] = gq==0 ? D1 : gq==1 ? R1 : gq==2 ? R3 : e1;
  return __builtin_bit_cast(half8, u);
}

// ---------------------------------------------------------------------------
// P3: flash attention v4.1. 8 waves x 16 q-rows, 512 threads, 2 blocks/CU =
// 16 waves/CU. V in LDS. phi+gp dbuf (48KB), counted vmcnt(3), swapped QK,
// in-reg softmax (xor32 on VALU), defer-max THR=8.
// ---------------------------------------------------------------------------
__global__ __launch_bounds__(512, 4) void attn_kernel(
    const float* __restrict__ x, const _Float16* __restrict__ phi,
    const _Float16* __restrict__ gpool, _Float16* __restrict__ y) {
  const int nt = blockIdx.x;           // 0..31
  const int b  = blockIdx.y;
  const int t  = threadIdx.x;
  const int w = t >> 6, l = t & 63, gq = (l >> 4) & 3, c16 = l & 15;

  __shared__ alignas(16) _Float16 phi_s[2][32*256];   // 16KB x 2
  __shared__ alignas(16) _Float16 gp_s[2][128*32];    // 8KB x 2

  // Q fragments (B-operand): 16 rows nt*128 + w*16 + c16
  half8 qf[8];
  {
    const int nq = nt*128 + w*16 + c16;
#pragma unroll
    for (int kk = 0; kk < 8; ++kk) {
      const int cb = kk*32 + gq*8;
      half8 q;
#pragma unroll
      for (int j = 0; j < 8; ++j) q[j] = (_Float16)x[((size_t)b*C_ + cb + j)*N_ + nq];
      qf[kk] = q;
    }
  }

  f32x4 yacc[8];
#pragma unroll
  for (int ds = 0; ds < 8; ++ds) yacc[ds] = (f32x4){0.f,0.f,0.f,0.f};
  float m_run = -INFINITY, l_run = 0.f;

  const int lhi = l >> 5, l31 = l & 31;

  auto stage = [&](int buf, int ch2) {
    const int m0 = ch2 * 32;
    // phi chunk 16KB = 16 slots (2/wave). plane p = 2j+lhi, row m = l31.
#pragma unroll
    for (int jj = 0; jj < 2; ++jj) {
      const int j = w*2 + jj;
      const char* src = (const char*)phi + ((size_t)(b*M_ + m0 + l31))*512 + (2*j + lhi)*16;
      gl2lds16(src, (char*)&phi_s[buf][0] + j*1024);
    }
    // gp chunk 8KB = 8 slots (1/wave). plane = w>>1, d = (w&1)*64 + l.
    {
      const char* src = (const char*)gpool + (((size_t)(b*D_ + (w&1)*64 + l))*M_ + m0)*2 + (w>>1)*16;
      gl2lds16(src, (char*)&gp_s[buf][0] + w*1024);
    }
  };

  stage(0, 0);

  const char* pAbase = (const char*)&phi_s[0][0] + gq*512 + c16*16;
  const char* pBbase = (const char*)&gp_s[0][0] + gq*2048 + c16*16;

  for (int ch = 0; ch < NCH; ++ch) {
    const int cur = ch & 1;
    if (ch + 1 < NCH) {
      stage(cur ^ 1, ch + 1);
      asm volatile("s_waitcnt vmcnt(3)" ::: "memory");   // stage(ch) landed
    } else {
      asm volatile("s_waitcnt vmcnt(0)" ::: "memory");
    }
    __builtin_amdgcn_s_barrier();
    asm volatile("" ::: "memory");

    // ---- QK^T swapped: fS[mt] = S[m = mt*16+gq*4+r][q-col = c16]
    f32x4 fS[2];
    fS[0] = (f32x4){0.f,0.f,0.f,0.f}; fS[1] = (f32x4){0.f,0.f,0.f,0.f};
    const char* pA = pAbase + cur*16384;
    __builtin_amdgcn_s_setprio(1);
#pragma unroll
    for (int kk = 0; kk < 8; ++kk) {
      half8 a0 = *(const half8*)(pA + kk*2048);        // mt=0 rows
      half8 a1 = *(const half8*)(pA + kk*2048 + 256);  // mt=1 rows
      fS[0] = __builtin_amdgcn_mfma_f32_16x16x32_f16(a0, qf[kk], fS[0], 0, 0, 0);
      fS[1] = __builtin_amdgcn_mfma_f32_16x16x32_f16(a1, qf[kk], fS[1], 0, 0, 0);
    }
    __builtin_amdgcn_s_setprio(0);

    // ---- online softmax (per q-col, lane-local) + defer-max
    float cmax = fS[0][0];
#pragma unroll
    for (int mt = 0; mt < 2; ++mt)
#pragma unroll
      for (int r = 0; r < 4; ++r) cmax = fmaxf(cmax, fS[mt][r]);
    cmax = fmaxf(cmax, __shfl_xor(cmax, 16, 64));
    cmax = fmaxf(cmax, xor32f(cmax));
    if (__any(cmax - m_run > 8.0f)) {   // slow path: rescale
      const float mn = fmaxf(m_run, cmax);
      const float sc = __expf(m_run - mn);
      m_run = mn;
      l_run *= sc;
      const int sci = __float_as_int(sc);
#pragma unroll
      for (int r = 0; r < 4; ++r) {
        const float scn = __int_as_float(__builtin_amdgcn_ds_bpermute(4*(gq*4 + r), sci));
#pragma unroll
        for (int ds = 0; ds < 8; ++ds) yacc[ds][r] *= scn;
      }
    }
    float p0[4], p1[4];
    float rs = 0.f;
#pragma unroll
    for (int r = 0; r < 4; ++r) {
      p0[r] = __expf(fS[0][r] - m_run);
      p1[r] = __expf(fS[1][r] - m_run);
      rs += p0[r] + p1[r];
    }
    rs += __shfl_xor(rs, 16, 64);
    rs += xor32f(rs);
    l_run += rs;
    half8 pa = build_pa(p0, p1, gq);

    // ---- PV (V from LDS, conflict-free 16B-plane layout)
    const char* pB = pBbase + cur*8192;
    __builtin_amdgcn_s_setprio(1);
#pragma unroll
    for (int ds = 0; ds < 8; ++ds) {
      half8 bv = *(const half8*)(pB + ds*256);
      yacc[ds] = __builtin_amdgcn_mfma_f32_16x16x32_f16(pa, bv, yacc[ds], 0, 0, 0);
    }
    __builtin_amdgcn_s_setprio(0);

    asm volatile("" ::: "memory");
    __builtin_amdgcn_s_barrier();
    asm volatile("" ::: "memory");
  }

  // epilogue: broadcast 1/l from q=c16 lanes to (gq,r) rows, write y fp16
  {
    const float inv = 1.0f / l_run;
    const int invi = __float_as_int(inv);
#pragma unroll
    for (int r = 0; r < 4; ++r) {
      const float invn = __int_as_float(__builtin_amdgcn_ds_bpermute(4*(gq*4 + r), invi));
      const int n = nt*128 + w*16 + gq*4 + r;
      _Float16* yr = y + ((size_t)b*N_ + n)*D_ + c16;
#pragma unroll
      for (int ds = 0; ds < 8; ++ds) yr[ds*16] = (_Float16)(yacc[ds][r] * invn);
    }
  }
}

// ---------------------------------------------------------------------------
// P4a: W-conv recompute -> per-(block,channel) partial sum/sumsq. No atomics.
// grid (64 n-tiles of 64 rows, 16 b) = 1024 blocks (4/CU).
// ---------------------------------------------------------------------------
__global__ __launch_bounds__(256) void stats_partial_kernel(
    const _Float16* __restrict__ y, const _Float16* __restrict__ ww16,
    const float* __restrict__ w_b, float* __restrict__ psum,
    float* __restrict__ pssq) {
  const int nt = blockIdx.x, b = blockIdx.y, t = threadIdx.x;
  const int w = t >> 6, l = t & 63, g = l >> 4, c16 = l & 15;
  const int n0 = nt*64;

  f32x4 acc[4][4];
#pragma unroll
  for (int a = 0; a < 4; ++a)
#pragma unroll
    for (int n = 0; n < 4; ++n) acc[a][n] = (f32x4){0.f,0.f,0.f,0.f};

#pragma unroll
  for (int kk = 0; kk < 4; ++kk) {
    const int d0 = kk*32 + g*8;
    half8 af[4];
#pragma unroll
    for (int cs = 0; cs < 4; ++cs)
      af[cs] = *(const half8*)(ww16 + (size_t)(w*64 + cs*16 + c16)*D_ + d0);
#pragma unroll
    for (int ns = 0; ns < 4; ++ns) {
      const int nn = n0 + ns*16 + c16;
      half8 bf = *(const half8*)&y[((size_t)b*N_ + nn)*D_ + d0];
#pragma unroll
      for (int cs = 0; cs < 4; ++cs)
        acc[cs][ns] = __builtin_amdgcn_mfma_f32_16x16x32_f16(af[cs], bf, acc[cs][ns], 0, 0, 0);
    }
  }

  const int blk = b*64 + nt;
#pragma unroll
  for (int cs = 0; cs < 4; ++cs)
#pragma unroll
    for (int r = 0; r < 4; ++r) {
      const int c = w*64 + cs*16 + g*4 + r;
      const float wb = w_b[c];
      float s = 0.f, q = 0.f;
#pragma unroll
      for (int ns = 0; ns < 4; ++ns) {
        const float v = acc[cs][ns][r] + wb;
        s += v; q += v*v;
      }
      s += __shfl_xor(s, 1, 64); s += __shfl_xor(s, 2, 64);
      s += __shfl_xor(s, 4, 64); s += __shfl_xor(s, 8, 64);
      q += __shfl_xor(q, 1, 64); q += __shfl_xor(q, 2, 64);
      q += __shfl_xor(q, 4, 64); q += __shfl_xor(q, 8, 64);
      if (c16 == 0) {
        psum[blk*C_ + c] = s;
        pssq[blk*C_ + c] = q;
      }
    }
}

// ---------------------------------------------------------------------------
// P4a2: reduce 1024 partials -> bnsum/bnssq. grid 8 blocks x 256t.
// ---------------------------------------------------------------------------
__global__ __launch_bounds__(256) void stats_reduce_kernel(
    const float* __restrict__ psum, const float* __restrict__ pssq,
    float* __restrict__ bnsum, float* __restrict__ bnssq) {
  const int t = threadIdx.x;
  const int ci = t & 31, bi = t >> 5;
  const int c = blockIdx.x*32 + ci;
  float s = 0.f, q = 0.f;
  for (int k = 0; k < 128; ++k) {
    const int row = bi + k*8;
    s += psum[row*C_ + c];
    q += pssq[row*C_ + c];
  }
  __shared__ float rs[8][32], rq[8][32];
  rs[bi][ci] = s; rq[bi][ci] = q;
  __syncthreads();
  if (bi == 0) {
    float S = 0.f, Q = 0.f;
#pragma unroll
    for (int k2 = 0; k2 < 8; ++k2) { S += rs[k2][ci]; Q += rq[k2][ci]; }
    bnsum[c] = S; bnssq[c] = Q;
  }
}

// ---------------------------------------------------------------------------
// P4b: W-conv recompute (fp16 y) + BatchNorm + residual -> out[b][c][n] f32
// ---------------------------------------------------------------------------
__global__ __launch_bounds__(256) void wconv_bn_kernel(
    const _Float16* __restrict__ y, const _Float16* __restrict__ ww16,
    const float* __restrict__ w_b, const float* __restrict__ bnsum,
    const float* __restrict__ bnssq, const float* __restrict__ gamma,
    const float* __restrict__ beta, const float* __restrict__ x,
    float* __restrict__ out) {
  const int nt = blockIdx.x, b = blockIdx.y, t = threadIdx.x;
  const int w = t >> 6, l = t & 63, g = l >> 4, c16 = l & 15;
  const int n0 = nt*64;

  f32x4 acc[4][4];
#pragma unroll
  for (int a = 0; a < 4; ++a)
#pragma unroll
    for (int n = 0; n < 4; ++n) acc[a][n] = (f32x4){0.f,0.f,0.f,0.f};

#pragma unroll
  for (int kk = 0; kk < 4; ++kk) {
    const int d0 = kk*32 + g*8;
    half8 af[4];
#pragma unroll
    for (int cs = 0; cs < 4; ++cs)
      af[cs] = *(const half8*)(ww16 + (size_t)(w*64 + cs*16 + c16)*D_ + d0);
#pragma unroll
    for (int ns = 0; ns < 4; ++ns) {
      const int nn = n0 + ns*16 + c16;
      half8 bf = *(const half8*)&y[((size_t)b*N_ + nn)*D_ + d0];
#pragma unroll
      for (int cs = 0; cs < 4; ++cs)
        acc[cs][ns] = __builtin_amdgcn_mfma_f32_16x16x32_f16(af[cs], bf, acc[cs][ns], 0, 0, 0);
    }
  }

  const float inv_cnt = 1.0f / (float)((size_t)B_ * N_);
#pragma unroll
  for (int cs = 0; cs < 4; ++cs) {
#pragma unroll
    for (int r = 0; r < 4; ++r) {
      const int c = w*64 + cs*16 + g*4 + r;
      const float wb  = w_b[c];
      const float mean = bnsum[c] * inv_cnt;
      const float var  = bnssq[c] * inv_cnt - mean*mean;
      const float istd = rsqrtf(var + 1e-5f);
      const float ga = gamma[c], be = beta[c];
#pragma unroll
      for (int ns = 0; ns < 4; ++ns) {
        const int n = n0 + ns*16 + c16;
        const size_t idx = ((size_t)b*C_ + c)*N_ + n;
        const float v = acc[cs][ns][r] + wb;
        out[idx] = (v - mean)*istd*ga + be + x[idx];
      }
    }
  }
}

// ---------------------------------------------------------------------------
extern "C" void kernel_launch(void* const* d_in, const int* in_sizes, int n_in,
                              void* d_out, int out_size, void* d_ws, size_t ws_size,
                              hipStream_t stream) {
  const float* x     = (const float*)d_in[0];
  const float* g_w   = (const float*)d_in[1];
  const float* g_b   = (const float*)d_in[2];
  const float* w_w   = (const float*)d_in[3];
  const float* w_b   = (const float*)d_in[4];
  const float* gamma = (const float*)d_in[5];
  const float* beta  = (const float*)d_in[6];
  float* out = (float*)d_out;

  char* ws = (char*)d_ws;
  _Float16* phi   = (_Float16*)(ws + WS_PHI);
  _Float16* gpool = (_Float16*)(ws + WS_GPOOL);
  _Float16* yb    = (_Float16*)(ws + WS_Y);
  float*    bnsum = (float*)(ws + WS_BNSUM);
  float*    bnssq = (float*)(ws + WS_BNSSQ);
  float*    psum  = (float*)(ws + WS_PSUM);
  float*    pssq  = (float*)(ws + WS_PSSQ);
  _Float16* gw16  = (_Float16*)(ws + WS_GW16);
  _Float16* ww16  = (_Float16*)(ws + WS_WW16);

  conv16_kernel<<<128, 256, 0, stream>>>(g_w, w_w, gw16, ww16);
  fused_pre_kernel<<<dim3(32, 16), 512, 0, stream>>>(x, gw16, g_b, phi, gpool);
  attn_kernel<<<dim3(32, 16), 512, 0, stream>>>(x, phi, gpool, yb);
  stats_partial_kernel<<<dim3(64, 16), 256, 0, stream>>>(yb, ww16, w_b, psum, pssq);
  stats_reduce_kernel<<<8, 256, 0, stream>>>(psum, pssq, bnsum, bnssq);
  wconv_bn_kernel<<<dim3(64, 16), 256, 0, stream>>>(yb, ww16, w_b, bnsum, bnssq, gamma, beta, x, out);
}

// Round 10
// 189.464 us; speedup vs baseline: 1.0312x; 1.0312x over previous
//
#include <hip/hip_runtime.h>
#include <hip/hip_bf16.h>

typedef _Float16 half8 __attribute__((ext_vector_type(8)));
typedef float f32x4 __attribute__((ext_vector_type(4)));
typedef unsigned uint4e __attribute__((ext_vector_type(4)));
typedef unsigned uint2e __attribute__((ext_vector_type(2)));

#define B_ 16
#define C_ 256
#define D_ 128
#define H_ 64
#define W_ 64
#define N_ 4096   // H*W
#define M_ 1024   // (H/2)*(W/2)
#define NCH 32    // M/32 key chunks

// workspace layout (bytes)
static constexpr size_t WS_PHI   = 0;                                  // fp16 [B][M][C]   8 MB
static constexpr size_t WS_GPOOL = WS_PHI   + (size_t)B_*M_*C_*2;      // fp16 [B][D][M]   4 MB
static constexpr size_t WS_Y     = WS_GPOOL + (size_t)B_*D_*M_*2;      // fp16 [B][N][D]  16 MB
static constexpr size_t WS_BNSUM = WS_Y     + (size_t)B_*N_*D_*2;      // f32  [C]
static constexpr size_t WS_BNSSQ = WS_BNSUM + (size_t)C_*4;            // f32  [C]
static constexpr size_t WS_PSUM  = WS_BNSSQ + (size_t)C_*4;            // f32  [1024][256] 1MB
static constexpr size_t WS_PSSQ  = WS_PSUM  + (size_t)1024*256*4;      // f32  [1024][256] 1MB
static constexpr size_t WS_GW16  = WS_PSSQ  + (size_t)1024*256*4;      // fp16 [D][C] 64KB
static constexpr size_t WS_WW16  = WS_GW16  + (size_t)D_*C_*2;         // fp16 [C][D] 64KB

typedef __attribute__((address_space(3))) void lds_vt;
typedef const __attribute__((address_space(1))) void gbl_vt;

__device__ __forceinline__ void gl2lds16(const void* g, void* s) {
  __builtin_amdgcn_global_load_lds((gbl_vt*)g, (lds_vt*)s, 16, 0, 0);
}

__device__ __forceinline__ unsigned pkrtz(float a, float b) {
  auto v = __builtin_amdgcn_cvt_pkrtz(a, b);   // __fp16 ext_vector(2)
  return __builtin_bit_cast(unsigned, v);
}

// xor-32 lane exchange on the VALU pipe (permlane32_swap) instead of LDS.
__device__ __forceinline__ unsigned xor32_swap(unsigned v) {
#if __has_builtin(__builtin_amdgcn_permlane32_swap)
  auto pr = __builtin_amdgcn_permlane32_swap(v, v, false, false);
  uint2e p = __builtin_bit_cast(uint2e, pr);
  return (threadIdx.x & 32) ? p[0] : p[1];
#else
  return __shfl_xor(v, 32, 64);
#endif
}
__device__ __forceinline__ float xor32f(float v) {
  return __builtin_bit_cast(float, xor32_swap(__builtin_bit_cast(unsigned, v)));
}

// ---------------------------------------------------------------------------
// P0: convert weights to fp16 once. gw16[d][c], ww16[c][d].
// ---------------------------------------------------------------------------
__global__ __launch_bounds__(256) void conv16_kernel(
    const float* __restrict__ gw, const float* __restrict__ ww,
    _Float16* __restrict__ gw16, _Float16* __restrict__ ww16) {
  const int i = blockIdx.x*256 + threadIdx.x;   // 0..32767
  gw16[i] = (_Float16)gw[i];
  ww16[i] = (_Float16)ww[i];
}

// ---------------------------------------------------------------------------
// P1+P2 fused: LDS-staged x slab (fp16 [256c][130n] padded), coalesced float4
// staging. phi = fp16(maxpool2x2(x)); gpool = fp16(maxpool2x2(g_w*.x)+g_b).
// ---------------------------------------------------------------------------
__global__ __launch_bounds__(512, 4) void fused_pre_kernel(
    const float* __restrict__ x, const _Float16* __restrict__ gw16,
    const float* __restrict__ g_b, _Float16* __restrict__ phi,
    _Float16* __restrict__ gpool) {
  const int i = blockIdx.x;            // image row-pair (rows 2i, 2i+1)
  const int b = blockIdx.y;
  const int t = threadIdx.x;
  const int w = t >> 6, l = t & 63, gq = (l >> 4) & 3, c16 = l & 15;
  const int wn = w & 3, wd = w >> 2;

  __shared__ _Float16 x_s[256][130];   // 65 KB; odd dword pitch -> all banks

  {
    const float* xb = x + (size_t)b*C_*N_ + (size_t)i*128;
#pragma unroll
    for (int it = 0; it < 16; ++it) {
      const int id = it*512 + t;
      const int c = id >> 5, nq = id & 31;
      float4 u = *(const float4*)(xb + (size_t)c*N_ + nq*4);
      unsigned* dst = (unsigned*)&x_s[c][nq*4];
      dst[0] = pkrtz(u.x, u.y);
      dst[1] = pkrtz(u.z, u.w);
    }
  }
  __syncthreads();

  f32x4 acc[4][2];
#pragma unroll
  for (int ds = 0; ds < 4; ++ds) {
    acc[ds][0] = (f32x4){0.f,0.f,0.f,0.f};
    acc[ds][1] = (f32x4){0.f,0.f,0.f,0.f};
  }

  const int nn0 = wn*16 + c16;
  const int mrow = i*32 + wn*8 + (c16 >> 1);

  for (int kk = 0; kk < 8; ++kk) {
    const int c0 = kk*32 + gq*8;
    half8 bf0, bf1;
#pragma unroll
    for (int j = 0; j < 8; ++j) {
      bf0[j] = x_s[c0 + j][nn0];
      bf1[j] = x_s[c0 + j][nn0 + 64];
    }
    if (wd == 0) {
      half8 pk_;
#pragma unroll
      for (int j = 0; j < 8; ++j) {
        float v = fmaxf((float)bf0[j], (float)bf1[j]);
        v = fmaxf(v, __shfl_xor(v, 1, 64));
        pk_[j] = (_Float16)v;
      }
      if (!(l & 1))
        *(half8*)(phi + ((size_t)b*M_ + mrow)*C_ + c0) = pk_;
    }
#pragma unroll
    for (int ds = 0; ds < 4; ++ds) {
      half8 af = *(const half8*)(gw16 + (size_t)((wd*4 + ds)*16 + c16)*C_ + c0);
      acc[ds][0] = __builtin_amdgcn_mfma_f32_16x16x32_f16(af, bf0, acc[ds][0], 0, 0, 0);
      acc[ds][1] = __builtin_amdgcn_mfma_f32_16x16x32_f16(af, bf1, acc[ds][1], 0, 0, 0);
    }
  }

#pragma unroll
  for (int ds = 0; ds < 4; ++ds) {
#pragma unroll
    for (int r = 0; r < 4; ++r) {
      const int d = (wd*4 + ds)*16 + gq*4 + r;
      float v = fmaxf(acc[ds][0][r], acc[ds][1][r]);
      v = fmaxf(v, __shfl_xor(v, 1, 64));
      if (!(l & 1))
        gpool[((size_t)b*D_ + d)*M_ + mrow] = (_Float16)(v + g_b[d]);
    }
  }
}

// ---------------------------------------------------------------------------
// in-register P -> PV A-fragment build (xor16 via ds_swizzle, xor32 via VALU)
// ---------------------------------------------------------------------------
__device__ __forceinline__ half8 build_pa(const float p0[4], const float p1[4], int gq) {
  unsigned d0 = pkrtz(p0[0], p0[1]);
  unsigned d1 = pkrtz(p0[2], p0[3]);
  unsigned e0 = pkrtz(p1[0], p1[1]);
  unsigned e1 = pkrtz(p1[2], p1[3]);
  unsigned D0 = __shfl_xor(d0, 16, 64), D1 = __shfl_xor(d1, 16, 64);
  unsigned E0 = __shfl_xor(e0, 16, 64), E1 = __shfl_xor(e1, 16, 64);
  const bool lo = gq < 2;
  unsigned s0 = lo ? e0 : d0, s1 = lo ? e1 : d1;
  unsigned s2 = lo ? E0 : D0, s3 = lo ? E1 : D1;
  unsigned R0 = xor32_swap(s0), R1 = xor32_swap(s1);
  unsigned R2 = xor32_swap(s2), R3 = xor32_swap(s3);
  uint4e u;
  u[0] = gq==0 ? d0 : gq==1 ? R2 : gq==2 ? R0 : E0;
  u[1] = gq==0 ? d1 : gq==1 ? R3 : gq==2 ? R1 : E1;
  u[2] = gq==0 ? D0 : gq==1 ? R0 : gq==2 ? R2 : e0;
  u[3] = gq==0 ? D1 : gq==1 ? R1 : gq==2 ? R3 : e1;
  return __builtin_bit_cast(half8, u);
}

// ---------------------------------------------------------------------------
// P3: flash attention v5. 8 waves x 16 q-rows, 512 threads, 2 blocks/CU.
// TRIPLE-buffered LDS (72KB) -> ONE barrier per chunk:
//   iter ch: vmcnt(3); barrier; read buf ch%3; compute; stage buf (ch+2)%3.
// Race-free: barrier(ch) => all waves done reading buf (ch-1)%3 before any
// stage(ch+2) overwrites it; per-wave vmcnt(3) before barrier => all
// stage(ch) data landed before any wave reads it.
// ---------------------------------------------------------------------------
__global__ __launch_bounds__(512, 4) void attn_kernel(
    const float* __restrict__ x, const _Float16* __restrict__ phi,
    const _Float16* __restrict__ gpool, _Float16* __restrict__ y) {
  const int nt = blockIdx.x;           // 0..31
  const int b  = blockIdx.y;
  const int t  = threadIdx.x;
  const int w = t >> 6, l = t & 63, gq = (l >> 4) & 3, c16 = l & 15;

  __shared__ alignas(16) _Float16 phi_s[3][32*256];   // 16KB x 3
  __shared__ alignas(16) _Float16 gp_s[3][128*32];    // 8KB x 3

  // Q fragments (B-operand): 16 rows nt*128 + w*16 + c16
  half8 qf[8];
  {
    const int nq = nt*128 + w*16 + c16;
#pragma unroll
    for (int kk = 0; kk < 8; ++kk) {
      const int cb = kk*32 + gq*8;
      half8 q;
#pragma unroll
      for (int j = 0; j < 8; ++j) q[j] = (_Float16)x[((size_t)b*C_ + cb + j)*N_ + nq];
      qf[kk] = q;
    }
  }

  f32x4 yacc[8];
#pragma unroll
  for (int ds = 0; ds < 8; ++ds) yacc[ds] = (f32x4){0.f,0.f,0.f,0.f};
  float m_run = -INFINITY, l_run = 0.f;

  const int lhi = l >> 5, l31 = l & 31;

  auto stage = [&](int buf, int ch2) {
    const int m0 = ch2 * 32;
    // phi chunk 16KB = 16 slots (2/wave). plane p = 2j+lhi, row m = l31.
#pragma unroll
    for (int jj = 0; jj < 2; ++jj) {
      const int j = w*2 + jj;
      const char* src = (const char*)phi + ((size_t)(b*M_ + m0 + l31))*512 + (2*j + lhi)*16;
      gl2lds16(src, (char*)&phi_s[buf][0] + j*1024);
    }
    // gp chunk 8KB = 8 slots (1/wave). plane = w>>1, d = (w&1)*64 + l.
    {
      const char* src = (const char*)gpool + (((size_t)(b*D_ + (w&1)*64 + l))*M_ + m0)*2 + (w>>1)*16;
      gl2lds16(src, (char*)&gp_s[buf][0] + w*1024);
    }
  };

  stage(0, 0);
  stage(1, 1);

  const char* pAbase = (const char*)&phi_s[0][0] + gq*512 + c16*16;
  const char* pBbase = (const char*)&gp_s[0][0] + gq*2048 + c16*16;

  for (int ch = 0; ch < NCH; ++ch) {
    const int cur = ch % 3;
    if (ch < NCH - 1) {
      asm volatile("s_waitcnt vmcnt(3)" ::: "memory");   // stage(ch) landed
    } else {
      asm volatile("s_waitcnt vmcnt(0)" ::: "memory");
    }
    __builtin_amdgcn_s_barrier();
    asm volatile("" ::: "memory");

    // ---- QK^T swapped: fS[mt] = S[m = mt*16+gq*4+r][q-col = c16]
    f32x4 fS[2];
    fS[0] = (f32x4){0.f,0.f,0.f,0.f}; fS[1] = (f32x4){0.f,0.f,0.f,0.f};
    const char* pA = pAbase + cur*16384;
    __builtin_amdgcn_s_setprio(1);
#pragma unroll
    for (int kk = 0; kk < 8; ++kk) {
      half8 a0 = *(const half8*)(pA + kk*2048);        // mt=0 rows
      half8 a1 = *(const half8*)(pA + kk*2048 + 256);  // mt=1 rows
      fS[0] = __builtin_amdgcn_mfma_f32_16x16x32_f16(a0, qf[kk], fS[0], 0, 0, 0);
      fS[1] = __builtin_amdgcn_mfma_f32_16x16x32_f16(a1, qf[kk], fS[1], 0, 0, 0);
    }
    __builtin_amdgcn_s_setprio(0);

    // ---- online softmax (per q-col, lane-local) + defer-max
    float cmax = fS[0][0];
#pragma unroll
    for (int mt = 0; mt < 2; ++mt)
#pragma unroll
      for (int r = 0; r < 4; ++r) cmax = fmaxf(cmax, fS[mt][r]);
    cmax = fmaxf(cmax, __shfl_xor(cmax, 16, 64));
    cmax = fmaxf(cmax, xor32f(cmax));
    if (__any(cmax - m_run > 8.0f)) {   // slow path: rescale
      const float mn = fmaxf(m_run, cmax);
      const float sc = __expf(m_run - mn);
      m_run = mn;
      l_run *= sc;
      const int sci = __float_as_int(sc);
#pragma unroll
      for (int r = 0; r < 4; ++r) {
        const float scn = __int_as_float(__builtin_amdgcn_ds_bpermute(4*(gq*4 + r), sci));
#pragma unroll
        for (int ds = 0; ds < 8; ++ds) yacc[ds][r] *= scn;
      }
    }
    float p0[4], p1[4];
    float rs = 0.f;
#pragma unroll
    for (int r = 0; r < 4; ++r) {
      p0[r] = __expf(fS[0][r] - m_run);
      p1[r] = __expf(fS[1][r] - m_run);
      rs += p0[r] + p1[r];
    }
    rs += __shfl_xor(rs, 16, 64);
    rs += xor32f(rs);
    l_run += rs;
    half8 pa = build_pa(p0, p1, gq);

    // ---- PV (V from LDS, conflict-free 16B-plane layout)
    const char* pB = pBbase + cur*8192;
    __builtin_amdgcn_s_setprio(1);
#pragma unroll
    for (int ds = 0; ds < 8; ++ds) {
      half8 bv = *(const half8*)(pB + ds*256);
      yacc[ds] = __builtin_amdgcn_mfma_f32_16x16x32_f16(pa, bv, yacc[ds], 0, 0, 0);
    }
    __builtin_amdgcn_s_setprio(0);

    // ---- prefetch chunk ch+2 into buf (ch+2)%3 (safe: all waves past
    //      barrier(ch) => done reading buf (ch-1)%3 == (ch+2)%3)
    if (ch + 2 < NCH) stage((ch + 2) % 3, ch + 2);
  }

  // epilogue: broadcast 1/l from q=c16 lanes to (gq,r) rows, write y fp16
  {
    const float inv = 1.0f / l_run;
    const int invi = __float_as_int(inv);
#pragma unroll
    for (int r = 0; r < 4; ++r) {
      const float invn = __int_as_float(__builtin_amdgcn_ds_bpermute(4*(gq*4 + r), invi));
      const int n = nt*128 + w*16 + gq*4 + r;
      _Float16* yr = y + ((size_t)b*N_ + n)*D_ + c16;
#pragma unroll
      for (int ds = 0; ds < 8; ++ds) yr[ds*16] = (_Float16)(yacc[ds][r] * invn);
    }
  }
}

// ---------------------------------------------------------------------------
// P4a: W-conv recompute -> per-(block,channel) partial sum/sumsq. No atomics.
// grid (64 n-tiles of 64 rows, 16 b) = 1024 blocks (4/CU).
// ---------------------------------------------------------------------------
__global__ __launch_bounds__(256) void stats_partial_kernel(
    const _Float16* __restrict__ y, const _Float16* __restrict__ ww16,
    const float* __restrict__ w_b, float* __restrict__ psum,
    float* __restrict__ pssq) {
  const int nt = blockIdx.x, b = blockIdx.y, t = threadIdx.x;
  const int w = t >> 6, l = t & 63, g = l >> 4, c16 = l & 15;
  const int n0 = nt*64;

  f32x4 acc[4][4];
#pragma unroll
  for (int a = 0; a < 4; ++a)
#pragma unroll
    for (int n = 0; n < 4; ++n) acc[a][n] = (f32x4){0.f,0.f,0.f,0.f};

#pragma unroll
  for (int kk = 0; kk < 4; ++kk) {
    const int d0 = kk*32 + g*8;
    half8 af[4];
#pragma unroll
    for (int cs = 0; cs < 4; ++cs)
      af[cs] = *(const half8*)(ww16 + (size_t)(w*64 + cs*16 + c16)*D_ + d0);
#pragma unroll
    for (int ns = 0; ns < 4; ++ns) {
      const int nn = n0 + ns*16 + c16;
      half8 bf = *(const half8*)&y[((size_t)b*N_ + nn)*D_ + d0];
#pragma unroll
      for (int cs = 0; cs < 4; ++cs)
        acc[cs][ns] = __builtin_amdgcn_mfma_f32_16x16x32_f16(af[cs], bf, acc[cs][ns], 0, 0, 0);
    }
  }

  const int blk = b*64 + nt;
#pragma unroll
  for (int cs = 0; cs < 4; ++cs)
#pragma unroll
    for (int r = 0; r < 4; ++r) {
      const int c = w*64 + cs*16 + g*4 + r;
      const float wb = w_b[c];
      float s = 0.f, q = 0.f;
#pragma unroll
      for (int ns = 0; ns < 4; ++ns) {
        const float v = acc[cs][ns][r] + wb;
        s += v; q += v*v;
      }
      s += __shfl_xor(s, 1, 64); s += __shfl_xor(s, 2, 64);
      s += __shfl_xor(s, 4, 64); s += __shfl_xor(s, 8, 64);
      q += __shfl_xor(q, 1, 64); q += __shfl_xor(q, 2, 64);
      q += __shfl_xor(q, 4, 64); q += __shfl_xor(q, 8, 64);
      if (c16 == 0) {
        psum[blk*C_ + c] = s;
        pssq[blk*C_ + c] = q;
      }
    }
}

// ---------------------------------------------------------------------------
// P4a2: reduce 1024 partials -> bnsum/bnssq. grid 8 blocks x 256t.
// ---------------------------------------------------------------------------
__global__ __launch_bounds__(256) void stats_reduce_kernel(
    const float* __restrict__ psum, const float* __restrict__ pssq,
    float* __restrict__ bnsum, float* __restrict__ bnssq) {
  const int t = threadIdx.x;
  const int ci = t & 31, bi = t >> 5;
  const int c = blockIdx.x*32 + ci;
  float s = 0.f, q = 0.f;
  for (int k = 0; k < 128; ++k) {
    const int row = bi + k*8;
    s += psum[row*C_ + c];
    q += pssq[row*C_ + c];
  }
  __shared__ float rs[8][32], rq[8][32];
  rs[bi][ci] = s; rq[bi][ci] = q;
  __syncthreads();
  if (bi == 0) {
    float S = 0.f, Q = 0.f;
#pragma unroll
    for (int k2 = 0; k2 < 8; ++k2) { S += rs[k2][ci]; Q += rq[k2][ci]; }
    bnsum[c] = S; bnssq[c] = Q;
  }
}

// ---------------------------------------------------------------------------
// P4b: W-conv recompute (fp16 y) + BatchNorm + residual -> out[b][c][n] f32
// ---------------------------------------------------------------------------
__global__ __launch_bounds__(256) void wconv_bn_kernel(
    const _Float16* __restrict__ y, const _Float16* __restrict__ ww16,
    const float* __restrict__ w_b, const float* __restrict__ bnsum,
    const float* __restrict__ bnssq, const float* __restrict__ gamma,
    const float* __restrict__ beta, const float* __restrict__ x,
    float* __restrict__ out) {
  const int nt = blockIdx.x, b = blockIdx.y, t = threadIdx.x;
  const int w = t >> 6, l = t & 63, g = l >> 4, c16 = l & 15;
  const int n0 = nt*64;

  f32x4 acc[4][4];
#pragma unroll
  for (int a = 0; a < 4; ++a)
#pragma unroll
    for (int n = 0; n < 4; ++n) acc[a][n] = (f32x4){0.f,0.f,0.f,0.f};

#pragma unroll
  for (int kk = 0; kk < 4; ++kk) {
    const int d0 = kk*32 + g*8;
    half8 af[4];
#pragma unroll
    for (int cs = 0; cs < 4; ++cs)
      af[cs] = *(const half8*)(ww16 + (size_t)(w*64 + cs*16 + c16)*D_ + d0);
#pragma unroll
    for (int ns = 0; ns < 4; ++ns) {
      const int nn = n0 + ns*16 + c16;
      half8 bf = *(const half8*)&y[((size_t)b*N_ + nn)*D_ + d0];
#pragma unroll
      for (int cs = 0; cs < 4; ++cs)
        acc[cs][ns] = __builtin_amdgcn_mfma_f32_16x16x32_f16(af[cs], bf, acc[cs][ns], 0, 0, 0);
    }
  }

  const float inv_cnt = 1.0f / (float)((size_t)B_ * N_);
#pragma unroll
  for (int cs = 0; cs < 4; ++cs) {
#pragma unroll
    for (int r = 0; r < 4; ++r) {
      const int c = w*64 + cs*16 + g*4 + r;
      const float wb  = w_b[c];
      const float mean = bnsum[c] * inv_cnt;
      const float var  = bnssq[c] * inv_cnt - mean*mean;
      const float istd = rsqrtf(var + 1e-5f);
      const float ga = gamma[c], be = beta[c];
#pragma unroll
      for (int ns = 0; ns < 4; ++ns) {
        const int n = n0 + ns*16 + c16;
        const size_t idx = ((size_t)b*C_ + c)*N_ + n;
        const float v = acc[cs][ns][r] + wb;
        out[idx] = (v - mean)*istd*ga + be + x[idx];
      }
    }
  }
}

// ---------------------------------------------------------------------------
extern "C" void kernel_launch(void* const* d_in, const int* in_sizes, int n_in,
                              void* d_out, int out_size, void* d_ws, size_t ws_size,
                              hipStream_t stream) {
  const float* x     = (const float*)d_in[0];
  const float* g_w   = (const float*)d_in[1];
  const float* g_b   = (const float*)d_in[2];
  const float* w_w   = (const float*)d_in[3];
  const float* w_b   = (const float*)d_in[4];
  const float* gamma = (const float*)d_in[5];
  const float* beta  = (const float*)d_in[6];
  float* out = (float*)d_out;

  char* ws = (char*)d_ws;
  _Float16* phi   = (_Float16*)(ws + WS_PHI);
  _Float16* gpool = (_Float16*)(ws + WS_GPOOL);
  _Float16* yb    = (_Float16*)(ws + WS_Y);
  float*    bnsum = (float*)(ws + WS_BNSUM);
  float*    bnssq = (float*)(ws + WS_BNSSQ);
  float*    psum  = (float*)(ws + WS_PSUM);
  float*    pssq  = (float*)(ws + WS_PSSQ);
  _Float16* gw16  = (_Float16*)(ws + WS_GW16);
  _Float16* ww16  = (_Float16*)(ws + WS_WW16);

  conv16_kernel<<<128, 256, 0, stream>>>(g_w, w_w, gw16, ww16);
  fused_pre_kernel<<<dim3(32, 16), 512, 0, stream>>>(x, gw16, g_b, phi, gpool);
  attn_kernel<<<dim3(32, 16), 512, 0, stream>>>(x, phi, gpool, yb);
  stats_partial_kernel<<<dim3(64, 16), 256, 0, stream>>>(yb, ww16, w_b, psum, pssq);
  stats_reduce_kernel<<<8, 256, 0, stream>>>(psum, pssq, bnsum, bnssq);
  wconv_bn_kernel<<<dim3(64, 16), 256, 0, stream>>>(yb, ww16, w_b, bnsum, bnssq, gamma, beta, x, out);
}